// Round 8
// baseline (1010.099 us; speedup 1.0000x reference)
//
#include <hip/hip_runtime.h>
#include <hip/hip_fp16.h>

#define N_NODES 100000
#define N_EDGES 3200000
#define N_GRAPHS 256
#define NODE_DIM 7
#define HID 64
#define NLAY 3
#define EPSV 1e-5f

#define NOCT 8
#define OCT_W 12800                  // 100 sub-bins of 128 nodes per octant
#define BIN_CAP 480000               // per-octant int2 capacity (mean ~409.6K)
#define SBW 128                      // sub-bin width (nodes)
#define NSB 782                      // ceil(100000/128)
#define SB_PER_OCT 100
#define CAP2 4608                    // per-sub-bin packed capacity (mean 4096, +8 sigma)
#define QN ((size_t)N_NODES * 16)    // halfs per feature-quarter table

static __device__ __forceinline__ void f4add(float4& a, const float4& b) {
    a.x += b.x; a.y += b.y; a.z += b.z; a.w += b.w;
}

// ---------------- graph-structure kernels (run once per call) ----------------

// batch is sorted: per-graph counts via binary search, zero atomics.
__global__ __launch_bounds__(256) void k_gcnt(const int* __restrict__ batch, int* __restrict__ gcnt) {
    __shared__ int start[N_GRAPHS + 1];
    int g = threadIdx.x;
    int lo = 0, hi = N_NODES;
    while (lo < hi) { int mid = (lo + hi) >> 1; if (batch[mid] < g) lo = mid + 1; else hi = mid; }
    start[g] = lo;
    if (g == 0) start[N_GRAPHS] = N_NODES;
    __syncthreads();
    gcnt[g] = start[g + 1] - start[g];
}

// Pass 1: bin edges by dst octant (width 12800). Dense int2 appends.
__global__ __launch_bounds__(256) void k_bin(const int* __restrict__ src, const int* __restrict__ dst,
                                             int* __restrict__ gcur, int2* __restrict__ bins) {
    __shared__ int lcnt[NOCT];
    __shared__ int lbase[NOCT];
    const int t = threadIdx.x;
    const int NC = N_EDGES / 4 / 256;              // 3125 chunks of 1024 edges
    for (int chunk = blockIdx.x; chunk < NC; chunk += gridDim.x) {
        if (t < NOCT) lcnt[t] = 0;
        __syncthreads();
        int i4 = chunk * 256 + t;
        int4 d = ((const int4*)dst)[i4];
        int4 s = ((const int4*)src)[i4];
        int o0 = d.x / OCT_W, o1 = d.y / OCT_W, o2 = d.z / OCT_W, o3 = d.w / OCT_W;
        int r0 = atomicAdd(&lcnt[o0], 1);
        int r1 = atomicAdd(&lcnt[o1], 1);
        int r2 = atomicAdd(&lcnt[o2], 1);
        int r3 = atomicAdd(&lcnt[o3], 1);
        __syncthreads();
        if (t < NOCT) lbase[t] = lcnt[t] ? atomicAdd(&gcur[t], lcnt[t]) : 0;
        __syncthreads();
        bins[(size_t)o0 * BIN_CAP + lbase[o0] + r0] = make_int2(d.x, s.x);
        bins[(size_t)o1 * BIN_CAP + lbase[o1] + r1] = make_int2(d.y, s.y);
        bins[(size_t)o2 * BIN_CAP + lbase[o2] + r2] = make_int2(d.z, s.z);
        bins[(size_t)o3 * BIN_CAP + lbase[o3] + r3] = make_int2(d.w, s.w);
        __syncthreads();
    }
}

// Pass 2a: octant bins -> per-sub-bin packed lists (src | dst_local<<17).
__global__ __launch_bounds__(256) void k_bin2a(const int2* __restrict__ bins1, const int* __restrict__ gcur,
                                               int* __restrict__ gcur2, unsigned* __restrict__ bins2) {
    __shared__ int lcnt[SB_PER_OCT];
    __shared__ int lbase[SB_PER_OCT];
    const int o = blockIdx.x & 7;
    const int slice = blockIdx.x >> 3;             // 0..31
    const int t = threadIdx.x;
    const int n = gcur[o];
    const int2* bp = bins1 + (size_t)o * BIN_CAP;
    const int sbBase = o * SB_PER_OCT;
    for (int start = slice * 2048; start < n; start += 32 * 2048) {
        if (t < SB_PER_OCT) lcnt[t] = 0;
        __syncthreads();
        int r[8]; int sbl[8]; unsigned pk[8];
#pragma unroll
        for (int j = 0; j < 8; j++) {
            int idx = start + j * 256 + t;
            if (idx < n) {
                int2 e = bp[idx];
                sbl[j] = (e.x - o * OCT_W) >> 7;
                pk[j] = (unsigned)e.y | ((unsigned)(e.x & (SBW - 1)) << 17);
                r[j] = atomicAdd(&lcnt[sbl[j]], 1);
            } else sbl[j] = -1;
        }
        __syncthreads();
        if (t < SB_PER_OCT) lbase[t] = lcnt[t] ? atomicAdd(&gcur2[sbBase + t], lcnt[t]) : 0;
        __syncthreads();
#pragma unroll
        for (int j = 0; j < 8; j++)
            if (sbl[j] >= 0)
                bins2[(size_t)(sbBase + sbl[j]) * CAP2 + lbase[sbl[j]] + r[j]] = pk[j];
        __syncthreads();
    }
}

// Pass 2b: per sub-bin LDS counting sort by dst_local -> CSR for free.
// Dense linear write-back; emits degE, dinv, rowptr2 with zero global atomics.
__global__ __launch_bounds__(256) void k_bin2s(unsigned* __restrict__ bins2, const int* __restrict__ gcur2,
                                               int* __restrict__ degE, float* __restrict__ dinv,
                                               int* __restrict__ rowptr2) {
    __shared__ unsigned raw[CAP2];
    __shared__ unsigned srt[CAP2];
    __shared__ int deg[SBW];
    __shared__ int cur[SBW];
    const int sb = blockIdx.x;
    const int t = threadIdx.x;
    const int base = sb * SBW;
    int n = gcur2[sb]; if (n > CAP2) n = CAP2;
    unsigned* seg = bins2 + (size_t)sb * CAP2;
    for (int i = t; i < n; i += 256) raw[i] = seg[i];
    if (t < SBW) deg[t] = 0;
    __syncthreads();
    for (int i = t; i < n; i += 256) atomicAdd(&deg[raw[i] >> 17], 1);
    __syncthreads();
    if (t == 0) {
        int run = 0;
        for (int i = 0; i < SBW; i++) { cur[i] = run; run += deg[i]; }
    }
    __syncthreads();
    if (t < SBW && base + t < N_NODES) {
        degE[base + t]   = deg[t];
        dinv[base + t]   = rsqrtf((float)(deg[t] + 1));     // +1 self-loop
        rowptr2[base + t] = sb * CAP2 + cur[t];
    }
    __syncthreads();
    for (int i = t; i < n; i += 256) {
        unsigned p = raw[i];
        srt[atomicAdd(&cur[p >> 17], 1)] = p;
    }
    __syncthreads();
    for (int i = t; i < n; i += 256) seg[i] = srt[i];
}

// ---------------- per-layer kernels ----------------

// h0 = x @ Win + bin
__global__ __launch_bounds__(256) void k_h0(const float* __restrict__ x, const float* __restrict__ Win,
                                            const float* __restrict__ b, float* __restrict__ h) {
    int i = blockIdx.x * 256 + threadIdx.x;
    if (i >= N_NODES * HID) return;
    int v = i >> 6, j = i & 63;
    float acc = b[j];
#pragma unroll
    for (int k = 0; k < NODE_DIM; k++) acc += x[v * NODE_DIM + k] * Win[k * HID + j];
    h[i] = acc;
}

// y = fp16( (h @ W) * dinv[:,None] ), written in feature-QUARTERED layout:
// y[(j>>4)*QN + node*16 + (j&15)], so each 16-feat table is 3.2MB (L2-resident).
__global__ __launch_bounds__(256) void k_xw(const float* __restrict__ h, const float* __restrict__ W,
                                            const float* __restrict__ dinv, __half* __restrict__ y) {
    __shared__ float Ws[HID][HID];
    __shared__ float Hs[64][HID];
    int t = threadIdx.x;
    int nb = blockIdx.x * 64;
#pragma unroll
    for (int it = 0; it < 4; it++) {
        int i = t + it * 256;
        ((float4*)Ws)[i] = ((const float4*)W)[i];
        int r = i >> 4, c4 = i & 15;
        int node = nb + r;
        float4 hv = make_float4(0.f, 0.f, 0.f, 0.f);
        if (node < N_NODES) hv = ((const float4*)h)[(size_t)node * 16 + c4];
        ((float4*)&Hs[r][0])[c4] = hv;
    }
    __syncthreads();
    int j = t & 63;
    int r0 = t >> 6;
    const size_t qoff = (size_t)(j >> 4) * QN + (j & 15);
#pragma unroll
    for (int o = 0; o < 4; o++) {
        int ra = r0 + o * 16;
        float a0 = 0.f, a1 = 0.f, a2 = 0.f, a3 = 0.f;
#pragma unroll
        for (int k4 = 0; k4 < 16; k4++) {
            float4 h0 = ((const float4*)&Hs[ra][0])[k4];
            float4 h1 = ((const float4*)&Hs[ra + 4][0])[k4];
            float4 h2 = ((const float4*)&Hs[ra + 8][0])[k4];
            float4 h3 = ((const float4*)&Hs[ra + 12][0])[k4];
            float w0 = Ws[k4 * 4 + 0][j];
            float w1 = Ws[k4 * 4 + 1][j];
            float w2 = Ws[k4 * 4 + 2][j];
            float w3 = Ws[k4 * 4 + 3][j];
            a0 += h0.x * w0 + h0.y * w1 + h0.z * w2 + h0.w * w3;
            a1 += h1.x * w0 + h1.y * w1 + h1.z * w2 + h1.w * w3;
            a2 += h2.x * w0 + h2.y * w1 + h2.z * w2 + h2.w * w3;
            a3 += h3.x * w0 + h3.y * w1 + h3.z * w2 + h3.w * w3;
        }
        int n0 = nb + ra, n1 = n0 + 4, n2 = n0 + 8, n3 = n0 + 12;
        if (n0 < N_NODES) y[qoff + (size_t)n0 * 16] = __float2half(a0 * dinv[n0]);
        if (n1 < N_NODES) y[qoff + (size_t)n1 * 16] = __float2half(a1 * dinv[n1]);
        if (n2 < N_NODES) y[qoff + (size_t)n2 * 16] = __float2half(a2 * dinv[n2]);
        if (n3 < N_NODES) y[qoff + (size_t)n3 * 16] = __float2half(a3 * dinv[n3]);
    }
}

// Feature-quartered aggregation, pass p: gather 32B rows from a 3.2MB
// L2-resident table. Wave per node; 4-lane edge-groups (16 edges / 512B
// wave-load, 2-deep unroll). Computes c[v][16p:16p+16) + stats slice.
__global__ __launch_bounds__(256) void k_agg4(const __half* __restrict__ yq,
                                              const int* __restrict__ rowptr2,
                                              const int* __restrict__ degE,
                                              const unsigned* __restrict__ cols,
                                              const float* __restrict__ dinv,
                                              const float* __restrict__ bias,
                                              const int* __restrict__ batch,
                                              float* __restrict__ c, int p,
                                              float* __restrict__ gS1, float* __restrict__ gS2) {
    __shared__ float sh1[4][16];
    __shared__ float sh2[4][16];
    __shared__ int shg[4];
    const int t = threadIdx.x;
    const int w = t >> 6, lane = t & 63;
    const int v = blockIdx.x * 4 + w;        // grid covers N_NODES exactly
    const int gg = lane >> 2;                // 16 edge-groups
    const int hq = lane & 3;                 // uint2 slot within 32B row
    const uint2* __restrict__ y8 = (const uint2*)yq;

    float a0 = 0.f, a1 = 0.f, a2 = 0.f, a3 = 0.f;
    float b0 = 0.f, b1 = 0.f, b2 = 0.f, b3 = 0.f;
    auto upA = [&](uint2 u) {
        float2 f0 = __half22float2(*(const __half2*)&u.x);
        float2 f1 = __half22float2(*(const __half2*)&u.y);
        a0 += f0.x; a1 += f0.y; a2 += f1.x; a3 += f1.y;
    };
    auto upB = [&](uint2 u) {
        float2 f0 = __half22float2(*(const __half2*)&u.x);
        float2 f1 = __half22float2(*(const __half2*)&u.y);
        b0 += f0.x; b1 += f0.y; b2 += f1.x; b3 += f1.y;
    };

    if (gg == 0) upA(y8[(size_t)v * 4 + hq]);          // self-loop
    const int e0 = rowptr2[v], e1 = e0 + degE[v];
    int e = e0 + gg;
    for (; e + 16 < e1; e += 32) {
        int s0 = cols[e] & 0x1FFFF;
        int s1 = cols[e + 16] & 0x1FFFF;
        uint2 u0 = y8[(size_t)s0 * 4 + hq];
        uint2 u1 = y8[(size_t)s1 * 4 + hq];
        upA(u0); upB(u1);
    }
    if (e < e1) upA(y8[(size_t)(cols[e] & 0x1FFFF) * 4 + hq]);
    a0 += b0; a1 += b1; a2 += b2; a3 += b3;
#pragma unroll
    for (int m = 4; m <= 32; m <<= 1) {
        a0 += __shfl_xor(a0, m); a1 += __shfl_xor(a1, m);
        a2 += __shfl_xor(a2, m); a3 += __shfl_xor(a3, m);
    }
    if (gg == 0) {   // lanes 0..3 hold feats [p*16+hq*4 .. +4)
        float dv = dinv[v];
        float4 bb = ((const float4*)bias)[p * 4 + hq];
        float4 cv = make_float4(dv * a0 + bb.x, dv * a1 + bb.y,
                                dv * a2 + bb.z, dv * a3 + bb.w);
        ((float4*)c)[(size_t)v * 16 + p * 4 + hq] = cv;
        sh1[w][hq * 4 + 0] = cv.x; sh2[w][hq * 4 + 0] = cv.x * cv.x;
        sh1[w][hq * 4 + 1] = cv.y; sh2[w][hq * 4 + 1] = cv.y * cv.y;
        sh1[w][hq * 4 + 2] = cv.z; sh2[w][hq * 4 + 2] = cv.z * cv.z;
        sh1[w][hq * 4 + 3] = cv.w; sh2[w][hq * 4 + 3] = cv.w * cv.w;
        if (hq == 0) shg[w] = batch[v];
    }
    __syncthreads();
    if (t < 16) {
        int g0 = shg[0];
        bool uni = (shg[1] == g0) && (shg[2] == g0) && (shg[3] == g0);
        int f = p * 16 + t;
        if (uni) {
            atomicAdd(&gS1[g0 * HID + f], sh1[0][t] + sh1[1][t] + sh1[2][t] + sh1[3][t]);
            atomicAdd(&gS2[g0 * HID + f], sh2[0][t] + sh2[1][t] + sh2[2][t] + sh2[3][t]);
        } else {
#pragma unroll
            for (int ww = 0; ww < 4; ww++) {
                atomicAdd(&gS1[shg[ww] * HID + f], sh1[ww][t]);
                atomicAdd(&gS2[shg[ww] * HID + f], sh2[ww][t]);
            }
        }
    }
}

// per-graph mean / inv-std.  var = S2/cnt - 2*s*m^2 + s^2*m^2
__global__ __launch_bounds__(256) void k_stats(const float* __restrict__ gS1, const float* __restrict__ gS2,
                                               const int* __restrict__ gcnt, const float* __restrict__ gnS_l,
                                               float* __restrict__ gmean, float* __restrict__ ginv) {
    int i = blockIdx.x * 256 + threadIdx.x;
    if (i >= N_GRAPHS * HID) return;
    int g = i >> 6, j = i & 63;
    float cnt = fmaxf((float)gcnt[g], 1.f);
    float m = gS1[i] / cnt;
    float s = gnS_l[j];
    float var = gS2[i] / cnt - 2.f * s * m * m + s * s * m * m;
    gmean[i] = m;
    ginv[i] = rsqrtf(var + EPSV);
}

// h += relu(gnW*(c - s*mean)*invstd + gnB), float4 lanes; 16 nodes/block;
// optional block-reduced graph-emb accumulation.
__global__ __launch_bounds__(256) void k_update(const float* __restrict__ c, const int* __restrict__ batch,
                                                const float* __restrict__ gmean, const float* __restrict__ ginv,
                                                const float* __restrict__ gnW_l, const float* __restrict__ gnB_l,
                                                const float* __restrict__ gnS_l, float* __restrict__ h,
                                                float* __restrict__ gemb, int accum_emb) {
    __shared__ float4 shh[16][16];
    __shared__ int shg[16];
    __shared__ int uniS;
    int t = threadIdx.x;
    int i = blockIdx.x * 256 + t;          // float4 index; grid covers N_NODES*16 exactly
    int v = i >> 4, f = i & 15, r = t >> 4;
    int g = batch[v];
    float4 c4 = ((const float4*)c)[i];
    float4 m4 = ((const float4*)gmean)[g * 16 + f];
    float4 i4 = ((const float4*)ginv)[g * 16 + f];
    float4 w4 = ((const float4*)gnW_l)[f];
    float4 b4 = ((const float4*)gnB_l)[f];
    float4 s4 = ((const float4*)gnS_l)[f];
    float4 h4 = ((const float4*)h)[i];
    float4 hn;
    hn.x = h4.x + fmaxf(w4.x * (c4.x - s4.x * m4.x) * i4.x + b4.x, 0.f);
    hn.y = h4.y + fmaxf(w4.y * (c4.y - s4.y * m4.y) * i4.y + b4.y, 0.f);
    hn.z = h4.z + fmaxf(w4.z * (c4.z - s4.z * m4.z) * i4.z + b4.z, 0.f);
    hn.w = h4.w + fmaxf(w4.w * (c4.w - s4.w * m4.w) * i4.w + b4.w, 0.f);
    ((float4*)h)[i] = hn;
    if (accum_emb) {
        shh[r][f] = hn;
        if (f == 0) shg[r] = g;
        if (t == 0) uniS = 1;
        __syncthreads();
        if (t < 15 && shg[t + 1] != shg[0]) uniS = 0;
        __syncthreads();
        if (uniS) {
            if (t < 128) f4add(shh[t >> 4][t & 15], shh[(t >> 4) + 8][t & 15]);
            __syncthreads();
            if (t < 64) f4add(shh[t >> 4][t & 15], shh[(t >> 4) + 4][t & 15]);
            __syncthreads();
            if (t < 32) f4add(shh[t >> 4][t & 15], shh[(t >> 4) + 2][t & 15]);
            __syncthreads();
            if (t < 16) {
                f4add(shh[0][t], shh[1][t]);
                float4 s = shh[0][t];
                int g0 = shg[0];
                atomicAdd(&gemb[g0 * HID + t * 4 + 0], s.x);
                atomicAdd(&gemb[g0 * HID + t * 4 + 1], s.y);
                atomicAdd(&gemb[g0 * HID + t * 4 + 2], s.z);
                atomicAdd(&gemb[g0 * HID + t * 4 + 3], s.w);
            }
        } else if (t < 16) {
#pragma unroll
            for (int rr = 0; rr < 16; rr++) {
                float4 s = shh[rr][t];
                int gg = shg[rr];
                atomicAdd(&gemb[gg * HID + t * 4 + 0], s.x);
                atomicAdd(&gemb[gg * HID + t * 4 + 1], s.y);
                atomicAdd(&gemb[gg * HID + t * 4 + 2], s.z);
                atomicAdd(&gemb[gg * HID + t * 4 + 3], s.w);
            }
        }
    }
}

// classifier head: emb = gemb/cnt ; z = relu(emb@W1+b1) ; out = z@W2+b2
__global__ __launch_bounds__(64) void k_cls(const float* __restrict__ gemb, const int* __restrict__ gcnt,
                                            const float* __restrict__ W1, const float* __restrict__ b1,
                                            const float* __restrict__ W2, const float* __restrict__ b2,
                                            float* __restrict__ out) {
    __shared__ float emb[HID];
    __shared__ float z[HID];
    int g = blockIdx.x, j = threadIdx.x;
    float cnt = fmaxf((float)gcnt[g], 1.f);
    emb[j] = gemb[g * HID + j] / cnt;
    __syncthreads();
    float acc = b1[j];
    for (int k = 0; k < HID; k++) acc += emb[k] * W1[k * HID + j];
    z[j] = fmaxf(acc, 0.f);
    __syncthreads();
    if (j < 2) {
        float o = b2[j];
        for (int k = 0; k < HID; k++) o += z[k] * W2[k * 2 + j];
        out[g * 2 + j] = o;
    }
}

extern "C" void kernel_launch(void* const* d_in, const int* in_sizes, int n_in,
                              void* d_out, int out_size, void* d_ws, size_t ws_size,
                              hipStream_t stream) {
    const float* x     = (const float*)d_in[0];
    const int*   ei    = (const int*)d_in[1];
    const int*   src   = ei;
    const int*   dst   = ei + N_EDGES;
    const int*   batch = (const int*)d_in[2];
    const float* Win   = (const float*)d_in[3];
    const float* bin_  = (const float*)d_in[4];
    const float* convW = (const float*)d_in[5];
    const float* convB = (const float*)d_in[6];
    const float* gnW   = (const float*)d_in[7];
    const float* gnB   = (const float*)d_in[8];
    const float* gnS   = (const float*)d_in[9];
    const float* W1    = (const float*)d_in[10];
    const float* b1    = (const float*)d_in[11];
    const float* W2    = (const float*)d_in[12];
    const float* b2    = (const float*)d_in[13];
    float* out = (float*)d_out;

    char* ws = (char*)d_ws;
    size_t off = 0;
    auto alloc = [&](size_t bytes) -> void* {
        void* p = ws + off;
        off = (off + bytes + 255) & ~(size_t)255;
        return p;
    };
    // ---- zeroed region (one memset) ----
    int*   gcur   = (int*)alloc(NOCT * 4);
    int*   gcur2  = (int*)alloc((size_t)NSB * 4);
    float* gS1    = (float*)alloc((size_t)NLAY * N_GRAPHS * HID * 4);
    float* gS2    = (float*)alloc((size_t)NLAY * N_GRAPHS * HID * 4);
    float* gemb   = (float*)alloc((size_t)N_GRAPHS * HID * 4);
    size_t zeroBytes = off;
    // ---- rest ----
    int*   gcnt   = (int*)alloc((size_t)N_GRAPHS * 4);
    int*   degE   = (int*)alloc((size_t)N_NODES * 4);
    float* dinv   = (float*)alloc((size_t)N_NODES * 4);
    int*   rowptr2= (int*)alloc((size_t)N_NODES * 4);
    float* h      = (float*)alloc((size_t)N_NODES * HID * 4);   // 25.6 MB
    __half* y     = (__half*)alloc((size_t)N_NODES * HID * 2);  // 12.8 MB (4 x 3.2MB quarters)
    float* c      = (float*)alloc((size_t)N_NODES * HID * 4);   // 25.6 MB
    unsigned* bins2 = (unsigned*)alloc((size_t)NSB * CAP2 * 4); // 14.4 MB (persists all layers)
    float* gmean  = (float*)alloc((size_t)N_GRAPHS * HID * 4);
    float* ginv   = (float*)alloc((size_t)N_GRAPHS * HID * 4);
    // bins1 (30.7 MB int2) aliases h+y (38.4 MB): dead before k_h0/k_xw write them.
    int2*  bins1  = (int2*)h;
    (void)ws_size; (void)in_sizes; (void)n_in; (void)out_size;

    hipMemsetAsync(d_ws, 0, zeroBytes, stream);

    const int NHB = (N_NODES * HID + 255) / 256;     // 25000

    k_gcnt<<<1, 256, 0, stream>>>(batch, gcnt);
    k_bin<<<800, 256, 0, stream>>>(src, dst, gcur, bins1);
    k_bin2a<<<256, 256, 0, stream>>>(bins1, gcur, gcur2, bins2);
    k_bin2s<<<NSB, 256, 0, stream>>>(bins2, gcur2, degE, dinv, rowptr2);

    k_h0<<<NHB, 256, 0, stream>>>(x, Win, bin_, h);

    const int XWB = (N_NODES + 63) / 64;             // 1563
    for (int l = 0; l < NLAY; l++) {
        const float* Wl   = convW + (size_t)l * HID * HID;
        const float* bl   = convB + (size_t)l * HID;
        const float* gnWl = gnW + (size_t)l * HID;
        const float* gnBl = gnB + (size_t)l * HID;
        const float* gnSl = gnS + (size_t)l * HID;
        float* S1l = gS1 + (size_t)l * N_GRAPHS * HID;
        float* S2l = gS2 + (size_t)l * N_GRAPHS * HID;

        k_xw<<<XWB, 256, 0, stream>>>(h, Wl, dinv, y);
        for (int p = 0; p < 4; p++)
            k_agg4<<<N_NODES / 4, 256, 0, stream>>>(y + (size_t)p * QN, rowptr2, degE, bins2,
                                                    dinv, bl, batch, c, p, S1l, S2l);
        k_stats<<<(N_GRAPHS * HID + 255) / 256, 256, 0, stream>>>(S1l, S2l, gcnt, gnSl, gmean, ginv);
        k_update<<<N_NODES * 16 / 256, 256, 0, stream>>>(c, batch, gmean, ginv, gnWl, gnBl, gnSl, h, gemb,
                                                         (l == NLAY - 1) ? 1 : 0);
    }

    k_cls<<<N_GRAPHS, 64, 0, stream>>>(gemb, gcnt, W1, b1, W2, b2, out);
}